// Round 4
// baseline (1157.554 us; speedup 1.0000x reference)
//
#include <hip/hip_runtime.h>
#include <cmath>

#define NLEV 16
#define TPB 256

typedef float v4f __attribute__((ext_vector_type(4)));
typedef float v2f __attribute__((ext_vector_type(2)));

// Level metadata replicated from the reference's _level_meta() (float64 host
// math; boundary levels 5/10/15 land 1e-5 ABOVE the integer -> res=65/257/1025).
static constexpr unsigned kRes[NLEV] = {16u,22u,28u,37u,49u,65u,85u,112u,148u,195u,257u,338u,446u,589u,777u,1025u};
static constexpr unsigned kMsz[NLEV] = {4096u,10648u,21952u,50656u,117656u,274632u,
  524288u,524288u,524288u,524288u,524288u,524288u,524288u,524288u,524288u,524288u};
static constexpr unsigned kOff[NLEV] = {0u,4096u,14744u,36696u,87352u,205008u,479640u,1003928u,
  1528216u,2052504u,2576792u,3101080u,3625368u,4149656u,4673944u,5198232u};
static constexpr int kDense[NLEV] = {1,1,1,1,1,1,0,0,0,0,0,0,0,0,0,0};

struct ScaleParams { float s[NLEV]; };

// 16-B load that is only guaranteed 8-B aligned (dense corner-pair load).
__device__ __forceinline__ v4f load4_a8(const float* p) {
  const float* q = (const float*)__builtin_assume_aligned((const void*)p, 8);
  v4f v;
  __builtin_memcpy(&v, q, 16);
  return v;
}

// Stage 512 points (2 per thread) of positions through LDS.
// stride 6 floats: gcd(6,32)=2 -> 2-way LDS aliasing, free on CDNA4.
__device__ __forceinline__ void load_pos2(const float* __restrict__ pos, float* sp,
                                          int tid, size_t pbase,
                                          float& px0, float& py0, float& pz0,
                                          float& px1, float& py1, float& pz1) {
  const float* src = pos + pbase * 3;
#pragma unroll
  for (int k = 0; k < 6; ++k)
    sp[tid + k * TPB] = __builtin_nontemporal_load(src + tid + k * TPB);
  __syncthreads();
  px0 = sp[tid * 6 + 0]; py0 = sp[tid * 6 + 1]; pz0 = sp[tid * 6 + 2];
  px1 = sp[tid * 6 + 3]; py1 = sp[tid * 6 + 4]; pz1 = sp[tid * 6 + 5];
}

// ---------------------------------------------------------------------------
// DENSE (round-1 form, measured ~200us — fastest dense variant):
// 2 pts/thread, paired-corner 16B gathers (x and x+1 corners are adjacent
// table entries), branchless wrap patch from a hoisted scalar load of entry 0.
// Accumulation order matches the reference 8-corner loop exactly.
// ---------------------------------------------------------------------------

__device__ __forceinline__ v2f dense_point(const float2* __restrict__ tab2,
                                           float px, float py, float pz,
                                           float scale, unsigned r, unsigned msz,
                                           unsigned off) {
  const float x = px * scale + 0.5f;
  const float y = py * scale + 0.5f;
  const float z = pz * scale + 0.5f;
  const float xf = floorf(x), yf = floorf(y), zf = floorf(z);
  const float tx = x - xf, ty = y - yf, tz = z - zf;
  const unsigned xi = (unsigned)xf, yi = (unsigned)yf, zi = (unsigned)zf;

  const unsigned hy[2] = {yi * r, (yi + 1u) * r};
  const unsigned hz[2] = {zi * r * r, (zi + 1u) * r * r};
  const float wx0 = 1.0f - tx, wx1 = tx;
  const float wy[2] = {1.0f - ty, ty};
  const float wz[2] = {1.0f - tz, tz};

  // wrap-patch value: corner x+1 of cell with idx==msz-1 lives at entry 0.
  const float2 g = tab2[off];

  float a0 = 0.0f, a1 = 0.0f;
#pragma unroll
  for (int c = 0; c < 4; ++c) {
    const unsigned h = xi + hy[c & 1] + hz[c >> 1];
    const unsigned idx = (h >= msz) ? (h - msz) : h;
    v4f f = load4_a8((const float*)(tab2 + (off + idx)));
    const bool wrap = (idx == msz - 1u);
    f.z = wrap ? g.x : f.z;
    f.w = wrap ? g.y : f.w;
    const float wyv = wy[c & 1], wzv = wz[c >> 1];
    const float w0 = (wx0 * wyv) * wzv;
    const float w1 = (wx1 * wyv) * wzv;
    a0 = fmaf(w0, f.x, a0);
    a1 = fmaf(w0, f.y, a1);
    a0 = fmaf(w1, f.z, a0);
    a1 = fmaf(w1, f.w, a1);
  }
  v2f rr; rr.x = a0; rr.y = a1;
  return rr;
}

__global__ __launch_bounds__(TPB, 4) void dense_levels2(
    const float* __restrict__ pos, const float* __restrict__ table,
    float* __restrict__ ws, ScaleParams spar, int npts)
{
  __shared__ float sp[TPB * 6];
  const int tid = threadIdx.x;
  const size_t pbase = (size_t)blockIdx.x * (TPB * 2);
  float px0, py0, pz0, px1, py1, pz1;
  load_pos2(pos, sp, tid, pbase, px0, py0, pz0, px1, py1, pz1);

  const float2* __restrict__ tab2 = (const float2*)table;
#pragma unroll
  for (int L = 0; L < 6; ++L) {
    const v2f r0 = dense_point(tab2, px0, py0, pz0, spar.s[L], kRes[L], kMsz[L], kOff[L]);
    const v2f r1 = dense_point(tab2, px1, py1, pz1, spar.s[L], kRes[L], kMsz[L], kOff[L]);
    v4f v; v.x = r0.x; v.y = r0.y; v.z = r1.x; v.w = r1.y;
    __builtin_nontemporal_store(v, (v4f*)ws + ((size_t)L * npts + pbase) / 2 + tid);
  }
}

// ---------------------------------------------------------------------------
// HASH (round-2 geometry, 2 pts/thread) with the round-4 experiment:
// 16 batched inline-asm global_load_dwordx2 sc0 gathers.
//  - sc0 bypasses L1 allocation (gathers always miss the 32KB L1 into a 4MB
//    table; the L1 miss/fill path is the suspected 0.55 req/cyc/CU wall).
//  - asm outputs cannot be sunk by the register allocator -> real 16-deep MLP
//    (rounds 1-3 showed source-level batching is always defeated: VGPR 32-48).
//  - s_waitcnt vmcnt(0) + sched_barrier(0) per rule #18 so consumers cannot
//    hoist above the hand-written waitcnt.
// ---------------------------------------------------------------------------

__global__ __launch_bounds__(TPB, 4) void hash_fused(
    const float* __restrict__ pos, const float* __restrict__ table,
    float* __restrict__ ws, ScaleParams spar, int lvlShift, int npts)
{
  __shared__ float sp[TPB * 6];
  const int tid = threadIdx.x;
  const int lvl = 6 + (int)(blockIdx.x >> lvlShift);
  const unsigned pb = blockIdx.x & ((1u << lvlShift) - 1u);

  // uniform scalar select of this block's scale (avoids dynamic kernarg index)
  float scale = 0.0f;
#pragma unroll
  for (int l = 6; l < NLEV; ++l) if (l == lvl) scale = spar.s[l];
  const unsigned off = kOff[6] + (unsigned)(lvl - 6) * 524288u;

  const size_t pbase = (size_t)pb * (TPB * 2);
  float px0, py0, pz0, px1, py1, pz1;
  float frac0[3], frac1[3];
  load_pos2(pos, sp, tid, pbase, px0, py0, pz0, px1, py1, pz1);

  unsigned i0[8], i1[8];
  {
    const float x = px0 * scale + 0.5f;
    const float y = py0 * scale + 0.5f;
    const float z = pz0 * scale + 0.5f;
    const float xf = floorf(x), yf = floorf(y), zf = floorf(z);
    frac0[0] = x - xf; frac0[1] = y - yf; frac0[2] = z - zf;
    const unsigned xi = (unsigned)xf, yi = (unsigned)yf, zi = (unsigned)zf;
    const unsigned hx[2] = {xi, xi + 1u};
    const unsigned hy[2] = {yi * 2654435761u, (yi + 1u) * 2654435761u};
    const unsigned hz[2] = {zi * 805459861u,  (zi + 1u) * 805459861u};
#pragma unroll
    for (int c = 0; c < 8; ++c)
      i0[c] = (hx[c & 1] ^ hy[(c >> 1) & 1] ^ hz[(c >> 2) & 1]) & 524287u;
  }
  {
    const float x = px1 * scale + 0.5f;
    const float y = py1 * scale + 0.5f;
    const float z = pz1 * scale + 0.5f;
    const float xf = floorf(x), yf = floorf(y), zf = floorf(z);
    frac1[0] = x - xf; frac1[1] = y - yf; frac1[2] = z - zf;
    const unsigned xi = (unsigned)xf, yi = (unsigned)yf, zi = (unsigned)zf;
    const unsigned hx[2] = {xi, xi + 1u};
    const unsigned hy[2] = {yi * 2654435761u, (yi + 1u) * 2654435761u};
    const unsigned hz[2] = {zi * 805459861u,  (zi + 1u) * 805459861u};
#pragma unroll
    for (int c = 0; c < 8; ++c)
      i1[c] = (hx[c & 1] ^ hy[(c >> 1) & 1] ^ hz[(c >> 2) & 1]) & 524287u;
  }

  // Batch-issue all 16 gathers with L1 bypass; dests are asm outputs so they
  // stay live from issue to consume (forced 16-deep MLP).
  const v2f* __restrict__ t2 = (const v2f*)table + off;
  v2f f0[8], f1[8];
#pragma unroll
  for (int c = 0; c < 8; ++c)
    asm volatile("global_load_dwordx2 %0, %1, off sc0"
                 : "=v"(f0[c]) : "v"(t2 + i0[c]) : "memory");
#pragma unroll
  for (int c = 0; c < 8; ++c)
    asm volatile("global_load_dwordx2 %0, %1, off sc0"
                 : "=v"(f1[c]) : "v"(t2 + i1[c]) : "memory");
  asm volatile("s_waitcnt vmcnt(0)" ::: "memory");
  __builtin_amdgcn_sched_barrier(0);   // rule #18: nothing hoists above the waitcnt

  const float wx0[2] = {1.0f - frac0[0], frac0[0]};
  const float wy0[2] = {1.0f - frac0[1], frac0[1]};
  const float wz0[2] = {1.0f - frac0[2], frac0[2]};
  const float wx1[2] = {1.0f - frac1[0], frac1[0]};
  const float wy1[2] = {1.0f - frac1[1], frac1[1]};
  const float wz1[2] = {1.0f - frac1[2], frac1[2]};

  float a0 = 0.0f, a1 = 0.0f, b0 = 0.0f, b1 = 0.0f;
#pragma unroll
  for (int c = 0; c < 8; ++c) {
    const float w = wx0[c & 1] * wy0[(c >> 1) & 1] * wz0[(c >> 2) & 1];
    a0 = fmaf(w, f0[c].x, a0);
    a1 = fmaf(w, f0[c].y, a1);
  }
#pragma unroll
  for (int c = 0; c < 8; ++c) {
    const float w = wx1[c & 1] * wy1[(c >> 1) & 1] * wz1[(c >> 2) & 1];
    b0 = fmaf(w, f1[c].x, b0);
    b1 = fmaf(w, f1[c].y, b1);
  }

  v4f v; v.x = a0; v.y = a1; v.z = b0; v.w = b1;
  __builtin_nontemporal_store(v, (v4f*)ws + ((size_t)lvl * npts + pbase) / 2 + tid);
}

__global__ __launch_bounds__(TPB, 4) void transpose_out(
    const float* __restrict__ ws, float* __restrict__ out, int npts)
{
  __shared__ float lds[TPB * 33];
  const int tid = threadIdx.x;
  const size_t pbase = (size_t)blockIdx.x * TPB;
#pragma unroll
  for (int L = 0; L < NLEV; ++L) {
    const v2f w = __builtin_nontemporal_load((const v2f*)ws + (size_t)L * npts + pbase + tid);
    lds[tid * 33 + 2 * L]     = w.x;
    lds[tid * 33 + 2 * L + 1] = w.y;
  }
  __syncthreads();
  v4f* out4 = (v4f*)out + (size_t)blockIdx.x * (TPB * 32 / 4);
#pragma unroll
  for (int k = 0; k < 8; ++k) {
    const int q  = tid + k * TPB;
    const int p  = q >> 3;
    const int c4 = (q & 7) * 4;
    v4f v;
    v.x = lds[p * 33 + c4 + 0];
    v.y = lds[p * 33 + c4 + 1];
    v.z = lds[p * 33 + c4 + 2];
    v.w = lds[p * 33 + c4 + 3];
    __builtin_nontemporal_store(v, out4 + q);
  }
}

// ---------------------------------------------------------------------------
// Fallback monolithic kernel (proven correct) if ws is too small or the grid
// geometry assumptions don't hold.
// ---------------------------------------------------------------------------
__global__ __launch_bounds__(TPB) void hashenc_kernel(
    const float* __restrict__ pos, const float* __restrict__ table,
    float* __restrict__ out, ScaleParams spar)
{
  __shared__ float lds[TPB * 33];
  const int tid = threadIdx.x;
  const size_t pbase = (size_t)blockIdx.x * TPB;
  {
    const float* src = pos + pbase * 3;
    lds[tid]        = src[tid];
    lds[tid + 256]  = src[tid + 256];
    lds[tid + 512]  = src[tid + 512];
  }
  __syncthreads();
  const float px = lds[tid*3 + 0];
  const float py = lds[tid*3 + 1];
  const float pz = lds[tid*3 + 2];
  __syncthreads();

  const float2* __restrict__ tab2 = (const float2*)table;
  float acc[2 * NLEV];

#pragma unroll
  for (int L = 0; L < NLEV; ++L) {
    const float scale = spar.s[L];
    const float x = px * scale + 0.5f;
    const float y = py * scale + 0.5f;
    const float z = pz * scale + 0.5f;
    const float xf = floorf(x), yf = floorf(y), zf = floorf(z);
    const float tx = x - xf, ty = y - yf, tz = z - zf;
    const unsigned xi = (unsigned)xf, yi = (unsigned)yf, zi = (unsigned)zf;

    unsigned hx[2], hy[2], hz[2];
    if (kDense[L]) {
      const unsigned r = kRes[L];
      hx[0] = xi;          hx[1] = xi + 1u;
      hy[0] = yi * r;      hy[1] = (yi + 1u) * r;
      hz[0] = zi * r * r;  hz[1] = (zi + 1u) * r * r;
    } else {
      hx[0] = xi;                 hx[1] = xi + 1u;
      hy[0] = yi * 2654435761u;   hy[1] = (yi + 1u) * 2654435761u;
      hz[0] = zi * 805459861u;    hz[1] = (zi + 1u) * 805459861u;
    }
    const float wx[2] = {1.0f - tx, tx};
    const float wy[2] = {1.0f - ty, ty};
    const float wz[2] = {1.0f - tz, tz};

    float a0 = 0.0f, a1 = 0.0f;
#pragma unroll
    for (int c = 0; c < 8; ++c) {
      unsigned idx;
      if (kDense[L]) {
        unsigned h = hx[c & 1] + hy[(c >> 1) & 1] + hz[(c >> 2) & 1];
        idx = (h >= kMsz[L]) ? (h - kMsz[L]) : h;
      } else {
        idx = (hx[c & 1] ^ hy[(c >> 1) & 1] ^ hz[(c >> 2) & 1]) & (kMsz[L] - 1u);
      }
      const float2 f = tab2[kOff[L] + idx];
      const float w = wx[c & 1] * wy[(c >> 1) & 1] * wz[(c >> 2) & 1];
      a0 = fmaf(w, f.x, a0);
      a1 = fmaf(w, f.y, a1);
    }
    acc[2 * L]     = a0;
    acc[2 * L + 1] = a1;
  }

#pragma unroll
  for (int c = 0; c < 32; ++c) lds[tid * 33 + c] = acc[c];
  __syncthreads();

  v4f* out4 = (v4f*)out + (size_t)blockIdx.x * (TPB * 32 / 4);
#pragma unroll
  for (int k = 0; k < 8; ++k) {
    const int q  = tid + k * TPB;
    const int p  = q >> 3;
    const int c4 = (q & 7) * 4;
    v4f v;
    v.x = lds[p * 33 + c4 + 0];
    v.y = lds[p * 33 + c4 + 1];
    v.z = lds[p * 33 + c4 + 2];
    v.w = lds[p * 33 + c4 + 3];
    __builtin_nontemporal_store(v, out4 + q);
  }
}

extern "C" void kernel_launch(void* const* d_in, const int* in_sizes, int n_in,
                              void* d_out, int out_size, void* d_ws, size_t ws_size,
                              hipStream_t stream) {
  const float* pos   = (const float*)d_in[0];
  const float* table = (const float*)d_in[1];
  float* out = (float*)d_out;

  ScaleParams sp;
  for (int i = 0; i < NLEV; ++i)
    sp.s[i] = (float)(16.0 * exp((double)i * log(1.3195079565048218)) - 1.0);

  const int npts = in_sizes[0] / 3;   // 2097152
  const size_t need = (size_t)npts * 32 * sizeof(float);

  const int npair = npts / (TPB * 2);            // blocks per level at 2 pts/thread
  int sh = 0; while ((1 << sh) < npair) ++sh;
  const bool ok = (npts % (TPB * 2) == 0) && ((1 << sh) == npair);

  if (ws_size >= need && ok) {
    float* wsf = (float*)d_ws;
    dense_levels2<<<npair, TPB, 0, stream>>>(pos, table, wsf, sp, npts);
    hash_fused<<<npair * 10, TPB, 0, stream>>>(pos, table, wsf, sp, sh, npts);
    transpose_out<<<npts / TPB, TPB, 0, stream>>>(wsf, out, npts);
  } else {
    hashenc_kernel<<<npts / TPB, TPB, 0, stream>>>(pos, table, out, sp);
  }
}

// Round 5
// 1003.445 us; speedup vs baseline: 1.1536x; 1.1536x over previous
//
#include <hip/hip_runtime.h>
#include <cmath>

#define NLEV 16
#define TPB 256

typedef float v4f __attribute__((ext_vector_type(4)));
typedef float v2f __attribute__((ext_vector_type(2)));

// Level metadata replicated from the reference's _level_meta() (float64 host
// math; boundary levels 5/10/15 land 1e-5 ABOVE the integer -> res=65/257/1025).
static constexpr unsigned kRes[NLEV] = {16u,22u,28u,37u,49u,65u,85u,112u,148u,195u,257u,338u,446u,589u,777u,1025u};
static constexpr unsigned kMsz[NLEV] = {4096u,10648u,21952u,50656u,117656u,274632u,
  524288u,524288u,524288u,524288u,524288u,524288u,524288u,524288u,524288u,524288u};
static constexpr unsigned kOff[NLEV] = {0u,4096u,14744u,36696u,87352u,205008u,479640u,1003928u,
  1528216u,2052504u,2576792u,3101080u,3625368u,4149656u,4673944u,5198232u};
static constexpr int kDense[NLEV] = {1,1,1,1,1,1,0,0,0,0,0,0,0,0,0,0};

struct ScaleParams { float s[NLEV]; };

// 16-B load that is only guaranteed 8-B aligned (dense corner-pair load).
__device__ __forceinline__ v4f load4_a8(const float* p) {
  const float* q = (const float*)__builtin_assume_aligned((const void*)p, 8);
  v4f v;
  __builtin_memcpy(&v, q, 16);
  return v;
}

// Stage 512 points (2 per thread) of positions through LDS.
// stride 6 floats: gcd(6,32)=2 -> 2-way LDS aliasing, free on CDNA4.
__device__ __forceinline__ void load_pos2(const float* __restrict__ pos, float* sp,
                                          int tid, size_t pbase,
                                          float& px0, float& py0, float& pz0,
                                          float& px1, float& py1, float& pz1) {
  const float* src = pos + pbase * 3;
#pragma unroll
  for (int k = 0; k < 6; ++k)
    sp[tid + k * TPB] = __builtin_nontemporal_load(src + tid + k * TPB);
  __syncthreads();
  px0 = sp[tid * 6 + 0]; py0 = sp[tid * 6 + 1]; pz0 = sp[tid * 6 + 2];
  px1 = sp[tid * 6 + 3]; py1 = sp[tid * 6 + 4]; pz1 = sp[tid * 6 + 5];
}

// ---------------------------------------------------------------------------
// DENSE (round-1 form, fastest measured dense variant ~200us):
// 2 pts/thread, paired-corner 16B gathers (x and x+1 corners are adjacent
// table entries), branchless wrap patch from a hoisted scalar load of entry 0.
// No sched_barrier: the compiler software-pipelines across the level loop.
// Accumulation order matches the reference 8-corner loop exactly.
// ---------------------------------------------------------------------------

__device__ __forceinline__ v2f dense_point(const float2* __restrict__ tab2,
                                           float px, float py, float pz,
                                           float scale, unsigned r, unsigned msz,
                                           unsigned off) {
  const float x = px * scale + 0.5f;
  const float y = py * scale + 0.5f;
  const float z = pz * scale + 0.5f;
  const float xf = floorf(x), yf = floorf(y), zf = floorf(z);
  const float tx = x - xf, ty = y - yf, tz = z - zf;
  const unsigned xi = (unsigned)xf, yi = (unsigned)yf, zi = (unsigned)zf;

  const unsigned hy[2] = {yi * r, (yi + 1u) * r};
  const unsigned hz[2] = {zi * r * r, (zi + 1u) * r * r};
  const float wx0 = 1.0f - tx, wx1 = tx;
  const float wy[2] = {1.0f - ty, ty};
  const float wz[2] = {1.0f - tz, tz};

  // wrap-patch value: corner x+1 of cell with idx==msz-1 lives at entry 0.
  const float2 g = tab2[off];

  float a0 = 0.0f, a1 = 0.0f;
#pragma unroll
  for (int c = 0; c < 4; ++c) {
    const unsigned h = xi + hy[c & 1] + hz[c >> 1];
    const unsigned idx = (h >= msz) ? (h - msz) : h;
    v4f f = load4_a8((const float*)(tab2 + (off + idx)));
    const bool wrap = (idx == msz - 1u);
    f.z = wrap ? g.x : f.z;
    f.w = wrap ? g.y : f.w;
    const float wyv = wy[c & 1], wzv = wz[c >> 1];
    const float w0 = (wx0 * wyv) * wzv;
    const float w1 = (wx1 * wyv) * wzv;
    a0 = fmaf(w0, f.x, a0);
    a1 = fmaf(w0, f.y, a1);
    a0 = fmaf(w1, f.z, a0);
    a1 = fmaf(w1, f.w, a1);
  }
  v2f rr; rr.x = a0; rr.y = a1;
  return rr;
}

__global__ __launch_bounds__(TPB, 4) void dense_levels2(
    const float* __restrict__ pos, const float* __restrict__ table,
    float* __restrict__ ws, ScaleParams spar, int npts)
{
  __shared__ float sp[TPB * 6];
  const int tid = threadIdx.x;
  const size_t pbase = (size_t)blockIdx.x * (TPB * 2);
  float px0, py0, pz0, px1, py1, pz1;
  load_pos2(pos, sp, tid, pbase, px0, py0, pz0, px1, py1, pz1);

  const float2* __restrict__ tab2 = (const float2*)table;
#pragma unroll
  for (int L = 0; L < 6; ++L) {
    const v2f r0 = dense_point(tab2, px0, py0, pz0, spar.s[L], kRes[L], kMsz[L], kOff[L]);
    const v2f r1 = dense_point(tab2, px1, py1, pz1, spar.s[L], kRes[L], kMsz[L], kOff[L]);
    v4f v; v.x = r0.x; v.y = r0.y; v.z = r1.x; v.w = r1.y;
    __builtin_nontemporal_store(v, (v4f*)ws + ((size_t)L * npts + pbase) / 2 + tid);
  }
}

// ---------------------------------------------------------------------------
// HASH (exact round-2 form — best measured: 492us, 0.55 lane-gathers/cyc/CU):
// one dispatch for all 10 hashed levels (level-major blocks keep each level's
// 4MB table L2-resident per XCD), 2 pts/thread, source-level batch of all 16
// gathers pinned by one sched_barrier, compiler-scheduled partial waitcnts.
// Rounds 3-4 proved: deeper batching (4pt), forced asm MLP, and L1 bypass all
// regress — the ~0.55 req/cyc/CU random-gather miss path is the wall.
// ---------------------------------------------------------------------------

__global__ __launch_bounds__(TPB, 4) void hash_fused(
    const float* __restrict__ pos, const float* __restrict__ table,
    float* __restrict__ ws, ScaleParams spar, int lvlShift, int npts)
{
  __shared__ float sp[TPB * 6];
  const int tid = threadIdx.x;
  const int lvl = 6 + (int)(blockIdx.x >> lvlShift);
  const unsigned pb = blockIdx.x & ((1u << lvlShift) - 1u);

  // uniform scalar select of this block's scale (avoids dynamic kernarg index)
  float scale = 0.0f;
#pragma unroll
  for (int l = 6; l < NLEV; ++l) if (l == lvl) scale = spar.s[l];
  const unsigned off = kOff[6] + (unsigned)(lvl - 6) * 524288u;

  const size_t pbase = (size_t)pb * (TPB * 2);
  float px0, py0, pz0, px1, py1, pz1;
  load_pos2(pos, sp, tid, pbase, px0, py0, pz0, px1, py1, pz1);

  unsigned i0[8], i1[8];
  float    w0[8], w1[8];
  {
    const float x = px0 * scale + 0.5f;
    const float y = py0 * scale + 0.5f;
    const float z = pz0 * scale + 0.5f;
    const float xf = floorf(x), yf = floorf(y), zf = floorf(z);
    const float tx = x - xf, ty = y - yf, tz = z - zf;
    const unsigned xi = (unsigned)xf, yi = (unsigned)yf, zi = (unsigned)zf;
    const unsigned hx[2] = {xi, xi + 1u};
    const unsigned hy[2] = {yi * 2654435761u, (yi + 1u) * 2654435761u};
    const unsigned hz[2] = {zi * 805459861u,  (zi + 1u) * 805459861u};
    const float wx[2] = {1.0f - tx, tx};
    const float wy[2] = {1.0f - ty, ty};
    const float wz[2] = {1.0f - tz, tz};
#pragma unroll
    for (int c = 0; c < 8; ++c) {
      i0[c] = (hx[c & 1] ^ hy[(c >> 1) & 1] ^ hz[(c >> 2) & 1]) & 524287u;
      w0[c] = wx[c & 1] * wy[(c >> 1) & 1] * wz[(c >> 2) & 1];
    }
  }
  {
    const float x = px1 * scale + 0.5f;
    const float y = py1 * scale + 0.5f;
    const float z = pz1 * scale + 0.5f;
    const float xf = floorf(x), yf = floorf(y), zf = floorf(z);
    const float tx = x - xf, ty = y - yf, tz = z - zf;
    const unsigned xi = (unsigned)xf, yi = (unsigned)yf, zi = (unsigned)zf;
    const unsigned hx[2] = {xi, xi + 1u};
    const unsigned hy[2] = {yi * 2654435761u, (yi + 1u) * 2654435761u};
    const unsigned hz[2] = {zi * 805459861u,  (zi + 1u) * 805459861u};
    const float wx[2] = {1.0f - tx, tx};
    const float wy[2] = {1.0f - ty, ty};
    const float wz[2] = {1.0f - tz, tz};
#pragma unroll
    for (int c = 0; c < 8; ++c) {
      i1[c] = (hx[c & 1] ^ hy[(c >> 1) & 1] ^ hz[(c >> 2) & 1]) & 524287u;
      w1[c] = wx[c & 1] * wy[(c >> 1) & 1] * wz[(c >> 2) & 1];
    }
  }

  const v2f* __restrict__ t2 = (const v2f*)table + off;
  v2f f0[8], f1[8];
#pragma unroll
  for (int c = 0; c < 8; ++c) f0[c] = t2[i0[c]];
#pragma unroll
  for (int c = 0; c < 8; ++c) f1[c] = t2[i1[c]];
  __builtin_amdgcn_sched_barrier(0);     // keep the gather group issued before use

  float a0 = 0.0f, a1 = 0.0f, b0 = 0.0f, b1 = 0.0f;
#pragma unroll
  for (int c = 0; c < 8; ++c) { a0 = fmaf(w0[c], f0[c].x, a0); a1 = fmaf(w0[c], f0[c].y, a1); }
#pragma unroll
  for (int c = 0; c < 8; ++c) { b0 = fmaf(w1[c], f1[c].x, b0); b1 = fmaf(w1[c], f1[c].y, b1); }

  v4f v; v.x = a0; v.y = a1; v.z = b0; v.w = b1;
  __builtin_nontemporal_store(v, (v4f*)ws + ((size_t)lvl * npts + pbase) / 2 + tid);
}

__global__ __launch_bounds__(TPB, 4) void transpose_out(
    const float* __restrict__ ws, float* __restrict__ out, int npts)
{
  __shared__ float lds[TPB * 33];
  const int tid = threadIdx.x;
  const size_t pbase = (size_t)blockIdx.x * TPB;
#pragma unroll
  for (int L = 0; L < NLEV; ++L) {
    const v2f w = __builtin_nontemporal_load((const v2f*)ws + (size_t)L * npts + pbase + tid);
    lds[tid * 33 + 2 * L]     = w.x;
    lds[tid * 33 + 2 * L + 1] = w.y;
  }
  __syncthreads();
  v4f* out4 = (v4f*)out + (size_t)blockIdx.x * (TPB * 32 / 4);
#pragma unroll
  for (int k = 0; k < 8; ++k) {
    const int q  = tid + k * TPB;
    const int p  = q >> 3;
    const int c4 = (q & 7) * 4;
    v4f v;
    v.x = lds[p * 33 + c4 + 0];
    v.y = lds[p * 33 + c4 + 1];
    v.z = lds[p * 33 + c4 + 2];
    v.w = lds[p * 33 + c4 + 3];
    __builtin_nontemporal_store(v, out4 + q);
  }
}

// ---------------------------------------------------------------------------
// Fallback monolithic kernel (proven correct) if ws is too small or the grid
// geometry assumptions don't hold.
// ---------------------------------------------------------------------------
__global__ __launch_bounds__(TPB) void hashenc_kernel(
    const float* __restrict__ pos, const float* __restrict__ table,
    float* __restrict__ out, ScaleParams spar)
{
  __shared__ float lds[TPB * 33];
  const int tid = threadIdx.x;
  const size_t pbase = (size_t)blockIdx.x * TPB;
  {
    const float* src = pos + pbase * 3;
    lds[tid]        = src[tid];
    lds[tid + 256]  = src[tid + 256];
    lds[tid + 512]  = src[tid + 512];
  }
  __syncthreads();
  const float px = lds[tid*3 + 0];
  const float py = lds[tid*3 + 1];
  const float pz = lds[tid*3 + 2];
  __syncthreads();

  const float2* __restrict__ tab2 = (const float2*)table;
  float acc[2 * NLEV];

#pragma unroll
  for (int L = 0; L < NLEV; ++L) {
    const float scale = spar.s[L];
    const float x = px * scale + 0.5f;
    const float y = py * scale + 0.5f;
    const float z = pz * scale + 0.5f;
    const float xf = floorf(x), yf = floorf(y), zf = floorf(z);
    const float tx = x - xf, ty = y - yf, tz = z - zf;
    const unsigned xi = (unsigned)xf, yi = (unsigned)yf, zi = (unsigned)zf;

    unsigned hx[2], hy[2], hz[2];
    if (kDense[L]) {
      const unsigned r = kRes[L];
      hx[0] = xi;          hx[1] = xi + 1u;
      hy[0] = yi * r;      hy[1] = (yi + 1u) * r;
      hz[0] = zi * r * r;  hz[1] = (zi + 1u) * r * r;
    } else {
      hx[0] = xi;                 hx[1] = xi + 1u;
      hy[0] = yi * 2654435761u;   hy[1] = (yi + 1u) * 2654435761u;
      hz[0] = zi * 805459861u;    hz[1] = (zi + 1u) * 805459861u;
    }
    const float wx[2] = {1.0f - tx, tx};
    const float wy[2] = {1.0f - ty, ty};
    const float wz[2] = {1.0f - tz, tz};

    float a0 = 0.0f, a1 = 0.0f;
#pragma unroll
    for (int c = 0; c < 8; ++c) {
      unsigned idx;
      if (kDense[L]) {
        unsigned h = hx[c & 1] + hy[(c >> 1) & 1] + hz[(c >> 2) & 1];
        idx = (h >= kMsz[L]) ? (h - kMsz[L]) : h;
      } else {
        idx = (hx[c & 1] ^ hy[(c >> 1) & 1] ^ hz[(c >> 2) & 1]) & (kMsz[L] - 1u);
      }
      const float2 f = tab2[kOff[L] + idx];
      const float w = wx[c & 1] * wy[(c >> 1) & 1] * wz[(c >> 2) & 1];
      a0 = fmaf(w, f.x, a0);
      a1 = fmaf(w, f.y, a1);
    }
    acc[2 * L]     = a0;
    acc[2 * L + 1] = a1;
  }

#pragma unroll
  for (int c = 0; c < 32; ++c) lds[tid * 33 + c] = acc[c];
  __syncthreads();

  v4f* out4 = (v4f*)out + (size_t)blockIdx.x * (TPB * 32 / 4);
#pragma unroll
  for (int k = 0; k < 8; ++k) {
    const int q  = tid + k * TPB;
    const int p  = q >> 3;
    const int c4 = (q & 7) * 4;
    v4f v;
    v.x = lds[p * 33 + c4 + 0];
    v.y = lds[p * 33 + c4 + 1];
    v.z = lds[p * 33 + c4 + 2];
    v.w = lds[p * 33 + c4 + 3];
    __builtin_nontemporal_store(v, out4 + q);
  }
}

extern "C" void kernel_launch(void* const* d_in, const int* in_sizes, int n_in,
                              void* d_out, int out_size, void* d_ws, size_t ws_size,
                              hipStream_t stream) {
  const float* pos   = (const float*)d_in[0];
  const float* table = (const float*)d_in[1];
  float* out = (float*)d_out;

  ScaleParams sp;
  for (int i = 0; i < NLEV; ++i)
    sp.s[i] = (float)(16.0 * exp((double)i * log(1.3195079565048218)) - 1.0);

  const int npts = in_sizes[0] / 3;   // 2097152
  const size_t need = (size_t)npts * 32 * sizeof(float);

  const int npair = npts / (TPB * 2);            // blocks per level at 2 pts/thread
  int sh = 0; while ((1 << sh) < npair) ++sh;
  const bool ok = (npts % (TPB * 2) == 0) && ((1 << sh) == npair);

  if (ws_size >= need && ok) {
    float* wsf = (float*)d_ws;
    dense_levels2<<<npair, TPB, 0, stream>>>(pos, table, wsf, sp, npts);
    hash_fused<<<npair * 10, TPB, 0, stream>>>(pos, table, wsf, sp, sh, npts);
    transpose_out<<<npts / TPB, TPB, 0, stream>>>(wsf, out, npts);
  } else {
    hashenc_kernel<<<npts / TPB, TPB, 0, stream>>>(pos, table, out, sp);
  }
}